// Round 1
// baseline (1071.257 us; speedup 1.0000x reference)
//
#include <hip/hip_runtime.h>
#include <hip/hip_bf16.h>
#include <cstdint>
#include <cstddef>

typedef __bf16 bf16;
typedef __attribute__((ext_vector_type(4))) __bf16 bf16x4;
typedef __attribute__((ext_vector_type(8))) __bf16 bf16x8;
typedef __attribute__((ext_vector_type(4))) float f32x4;

#define MFMA16(a, b, c) __builtin_amdgcn_mfma_f32_16x16x32_bf16((a), (b), (c), 0, 0, 0)

#define SCALE_F 0.08838834764831845f   // 1/sqrt(128)

// ---------------- f32 -> bf16 conversion ----------------
__global__ void k_cvt_f32_bf16(const float* __restrict__ in, bf16* __restrict__ out, int n4)
{
    int i = blockIdx.x * blockDim.x + threadIdx.x;
    int stride = gridDim.x * blockDim.x;
    const float4* in4 = (const float4*)in;
    bf16x4* o4 = (bf16x4*)out;
    for (; i < n4; i += stride) {
        float4 v = in4[i];
        bf16x4 o;
        o[0] = (bf16)v.x; o[1] = (bf16)v.y; o[2] = (bf16)v.z; o[3] = (bf16)v.w;
        o4[i] = o;
    }
}

// ---------------- generic bf16 MFMA GEMM ----------------
// C[M,N] = A[M,K] * B[K,N]; row-major. 128x128 block tile, 4 waves, each wave 64x64.
// AF32: A is read from f32 and converted during staging.  F32OUT: C written as f32.
template<bool AF32, bool F32OUT>
__global__ __launch_bounds__(256) void k_gemm(
    const bf16* __restrict__ A, const float* __restrict__ Af,
    const bf16* __restrict__ B,
    bf16* __restrict__ Cb, float* __restrict__ Cf,
    int M, int N, int K)
{
    __shared__ bf16 As[128 * 40];   // [row][k], stride 40 (pad) -> 2-way bank alias (free)
    __shared__ bf16 BsT[128 * 40];  // [col n][k], stride 40

    const int t = threadIdx.x;
    const int m0 = blockIdx.y * 128;
    const int n0 = blockIdx.x * 128;
    const int wid = t >> 6, lane = t & 63;
    const int wm = (wid >> 1) * 64, wn = (wid & 1) * 64;
    const int lr = lane & 15, lk = (lane >> 4) * 8;

    f32x4 acc[4][4];
    const f32x4 z = {0.f, 0.f, 0.f, 0.f};
#pragma unroll
    for (int m = 0; m < 4; ++m)
#pragma unroll
        for (int n = 0; n < 4; ++n) acc[m][n] = z;

    for (int k0 = 0; k0 < K; k0 += 32) {
        __syncthreads();
        // stage A tile 128x32 (chunks of 8 elems; 512 chunks / 256 threads)
#pragma unroll
        for (int i = 0; i < 2; ++i) {
            int idx = t + i * 256;
            int row = idx >> 2;
            int kc = (idx & 3) << 3;
            bf16x8 v;
            if (m0 + row < M) {
                if constexpr (AF32) {
                    const float* src = Af + (size_t)(m0 + row) * K + k0 + kc;
                    float4 u0 = *(const float4*)src;
                    float4 u1 = *(const float4*)(src + 4);
                    v[0] = (bf16)u0.x; v[1] = (bf16)u0.y; v[2] = (bf16)u0.z; v[3] = (bf16)u0.w;
                    v[4] = (bf16)u1.x; v[5] = (bf16)u1.y; v[6] = (bf16)u1.z; v[7] = (bf16)u1.w;
                } else {
                    v = *(const bf16x8*)(A + (size_t)(m0 + row) * K + k0 + kc);
                }
            } else {
#pragma unroll
                for (int j = 0; j < 8; ++j) v[j] = (bf16)0.f;
            }
            *(bf16x8*)(As + row * 40 + kc) = v;
        }
        // stage B tile 32x128, transposed into BsT[n][k]
#pragma unroll
        for (int i = 0; i < 2; ++i) {
            int idx = t + i * 256;
            int kk = idx >> 4;
            int nn = (idx & 15) << 3;
            bf16x8 v;
            if (n0 + nn < N) {
                v = *(const bf16x8*)(B + (size_t)(k0 + kk) * N + n0 + nn);
            } else {
#pragma unroll
                for (int j = 0; j < 8; ++j) v[j] = (bf16)0.f;
            }
#pragma unroll
            for (int j = 0; j < 8; ++j) BsT[(nn + j) * 40 + kk] = v[j];
        }
        __syncthreads();

        bf16x8 af[4], bfr[4];
#pragma unroll
        for (int m = 0; m < 4; ++m) af[m] = *(const bf16x8*)(As + (wm + m * 16 + lr) * 40 + lk);
#pragma unroll
        for (int n = 0; n < 4; ++n) bfr[n] = *(const bf16x8*)(BsT + (wn + n * 16 + lr) * 40 + lk);
#pragma unroll
        for (int m = 0; m < 4; ++m)
#pragma unroll
            for (int n = 0; n < 4; ++n)
                acc[m][n] = MFMA16(af[m], bfr[n], acc[m][n]);
    }

    const int lrow4 = (lane >> 4) * 4;
#pragma unroll
    for (int m = 0; m < 4; ++m)
#pragma unroll
        for (int n = 0; n < 4; ++n)
#pragma unroll
            for (int i = 0; i < 4; ++i) {
                int r = m0 + wm + m * 16 + lrow4 + i;
                int c = n0 + wn + n * 16 + lr;
                if (r < M && c < N) {
                    if constexpr (F32OUT) Cf[(size_t)r * N + c] = acc[m][n][i];
                    else Cb[(size_t)r * N + c] = (bf16)acc[m][n][i];
                }
            }
}

// ---------------- RoPE (in-place, bf16) ----------------
// q_r: [4096 rows][16 heads * 64]; pairs (2i, 2i+1) within each head's 64.
__global__ void k_rope_q(bf16* __restrict__ qr)
{
    int idx = blockIdx.x * blockDim.x + threadIdx.x;  // exactly 4096*512 threads
    int row = idx >> 9;
    int rem = idx & 511;
    int h = rem >> 5;
    int i = rem & 31;
    int s = row & 2047;
    float ang = (float)s * __expf(-(float)i * 0.28782313662f);  // ln(10000)/32
    float c = cosf(ang), sn = sinf(ang);
    int base = (row << 10) + (h << 6) + (i << 1);
    float xe = (float)qr[base], xo = (float)qr[base + 1];
    qr[base] = (bf16)(xe * c - xo * sn);
    qr[base + 1] = (bf16)(xe * sn + xo * c);
}

// k_r: [4096 rows][64]
__global__ void k_rope_k(bf16* __restrict__ kr)
{
    int idx = blockIdx.x * blockDim.x + threadIdx.x;  // exactly 4096*32 threads
    int row = idx >> 5;
    int i = idx & 31;
    int s = row & 2047;
    float ang = (float)s * __expf(-(float)i * 0.28782313662f);
    float c = cosf(ang), sn = sinf(ang);
    int base = (row << 6) + (i << 1);
    float xe = (float)kr[base], xo = (float)kr[base + 1];
    kr[base] = (bf16)(xe * c - xo * sn);
    kr[base + 1] = (bf16)(xe * sn + xo * c);
}

// ---------------- causal MLA attention (flash-style) ----------------
// Block: (qt, h, b). 4 waves x 16 q-rows = 64 q rows per block. KV tiles of 64.
// qc: [B*S][2048] (h*128+d); qr: [B*S][1024] (h*64+r);
// kv: [B*S][4096] (k_c at h*128+d, v at 2048+h*128+d); kr: [B*S][64]; att: [B*S][2048].
__global__ __launch_bounds__(256) void k_attn(
    const bf16* __restrict__ qc, const bf16* __restrict__ qr,
    const bf16* __restrict__ kv, const bf16* __restrict__ kr,
    bf16* __restrict__ att)
{
    __shared__ bf16 Ks[64 * 200];   // [key][feat 0..191], stride 200
    __shared__ bf16 Vt[128 * 72];   // [feat][key], stride 72
    __shared__ bf16 Pw[4][16 * 72]; // per-wave P tile [qrow16][key64], stride 72

    const int t = threadIdx.x;
    const int qt = blockIdx.x;
    const int h = blockIdx.y;
    const int b = blockIdx.z;
    const int wid = t >> 6, lane = t & 63;
    const int lr = lane & 15, lk = (lane >> 4) * 8, lrow4 = (lane >> 4) * 4;

    const size_t rowbase = (size_t)b * 2048;
    const int qrow = qt * 64 + wid * 16;

    // Q fragments: 4 k-steps over q_c's 128 feats + 2 over q_r's 64
    bf16x8 qf[6];
    {
        const bf16* qp = qc + (rowbase + qrow + lr) * 2048 + h * 128;
#pragma unroll
        for (int ks = 0; ks < 4; ++ks) qf[ks] = *(const bf16x8*)(qp + ks * 32 + lk);
        const bf16* qp2 = qr + (rowbase + qrow + lr) * 1024 + h * 64;
#pragma unroll
        for (int ks = 0; ks < 2; ++ks) qf[4 + ks] = *(const bf16x8*)(qp2 + ks * 32 + lk);
    }

    float mrow[4], lsum[4];
    f32x4 o[8];
    const f32x4 z = {0.f, 0.f, 0.f, 0.f};
#pragma unroll
    for (int i = 0; i < 4; ++i) { mrow[i] = -3e38f; lsum[i] = 0.f; }
#pragma unroll
    for (int n = 0; n < 8; ++n) o[n] = z;

    const int nkt = qt + 1;
    for (int kt = 0; kt < nkt; ++kt) {
        const int kb = kt * 64;
        __syncthreads();
        // stage K_c 64x128
#pragma unroll
        for (int i = 0; i < 4; ++i) {
            int idx = t + i * 256;
            int row = idx >> 4;
            int fc = (idx & 15) << 3;
            bf16x8 v = *(const bf16x8*)(kv + (rowbase + kb + row) * 4096 + h * 128 + fc);
            *(bf16x8*)(Ks + row * 200 + fc) = v;
        }
        // stage K_r 64x64
#pragma unroll
        for (int i = 0; i < 2; ++i) {
            int idx = t + i * 256;
            int row = idx >> 3;
            int fc = (idx & 7) << 3;
            bf16x8 v = *(const bf16x8*)(kr + (rowbase + kb + row) * 64 + fc);
            *(bf16x8*)(Ks + row * 200 + 128 + fc) = v;
        }
        // stage V transposed: Vt[feat][key]
#pragma unroll
        for (int i = 0; i < 4; ++i) {
            int idx = t + i * 256;
            int row = idx >> 4;
            int fc = (idx & 15) << 3;
            bf16x8 v = *(const bf16x8*)(kv + (rowbase + kb + row) * 4096 + 2048 + h * 128 + fc);
#pragma unroll
            for (int j = 0; j < 8; ++j) Vt[(fc + j) * 72 + row] = v[j];
        }
        __syncthreads();

        // S = Q K^T  (16 q-rows x 64 keys per wave)
        f32x4 sacc[4];
#pragma unroll
        for (int kg = 0; kg < 4; ++kg) {
            f32x4 s = z;
#pragma unroll
            for (int ks = 0; ks < 6; ++ks) {
                bf16x8 kf = *(const bf16x8*)(Ks + (kg * 16 + lr) * 200 + ks * 32 + lk);
                s = MFMA16(qf[ks], kf, s);
            }
            sacc[kg] = s;
        }

        // scale + causal mask + row max
        float rmax[4];
#pragma unroll
        for (int i = 0; i < 4; ++i) {
            int qi = qrow + lrow4 + i;
            float mx = -3e38f;
#pragma unroll
            for (int kg = 0; kg < 4; ++kg) {
                int kcol = kb + kg * 16 + lr;
                float v = sacc[kg][i] * SCALE_F;
                v = (kcol <= qi) ? v : -3e38f;
                sacc[kg][i] = v;
                mx = fmaxf(mx, v);
            }
            rmax[i] = mx;
        }
#pragma unroll
        for (int d = 1; d < 16; d <<= 1)
#pragma unroll
            for (int i = 0; i < 4; ++i)
                rmax[i] = fmaxf(rmax[i], __shfl_xor(rmax[i], d, 64));

        float scl[4];
#pragma unroll
        for (int i = 0; i < 4; ++i) {
            float mnew = fmaxf(mrow[i], rmax[i]);
            scl[i] = __expf(mrow[i] - mnew);
            mrow[i] = mnew;
        }
        float rsum[4] = {0.f, 0.f, 0.f, 0.f};
#pragma unroll
        for (int kg = 0; kg < 4; ++kg)
#pragma unroll
            for (int i = 0; i < 4; ++i) {
                float p = __expf(sacc[kg][i] - mrow[i]);
                sacc[kg][i] = p;
                rsum[i] += p;
            }
#pragma unroll
        for (int d = 1; d < 16; d <<= 1)
#pragma unroll
            for (int i = 0; i < 4; ++i) rsum[i] += __shfl_xor(rsum[i], d, 64);
#pragma unroll
        for (int i = 0; i < 4; ++i) lsum[i] = lsum[i] * scl[i] + rsum[i];
#pragma unroll
        for (int n = 0; n < 8; ++n)
#pragma unroll
            for (int i = 0; i < 4; ++i) o[n][i] *= scl[i];

        // P -> LDS (re-fragment for PV A-operand); same-wave DS ops are in-order
#pragma unroll
        for (int kg = 0; kg < 4; ++kg)
#pragma unroll
            for (int i = 0; i < 4; ++i)
                Pw[wid][(lrow4 + i) * 72 + kg * 16 + lr] = (bf16)sacc[kg][i];

        // O += P V
#pragma unroll
        for (int ks = 0; ks < 2; ++ks) {
            bf16x8 pa = *(const bf16x8*)(&Pw[wid][lr * 72 + ks * 32 + lk]);
#pragma unroll
            for (int n = 0; n < 8; ++n) {
                bf16x8 vf = *(const bf16x8*)(Vt + (n * 16 + lr) * 72 + ks * 32 + lk);
                o[n] = MFMA16(pa, vf, o[n]);
            }
        }
    }

#pragma unroll
    for (int i = 0; i < 4; ++i) {
        float inv = 1.f / lsum[i];
        size_t orow = (rowbase + qrow + lrow4 + i) * 2048 + h * 128;
#pragma unroll
        for (int n = 0; n < 8; ++n)
            att[orow + n * 16 + lr] = (bf16)(o[n][i] * inv);
    }
}

// ---------------- host launch ----------------
extern "C" void kernel_launch(void* const* d_in, const int* in_sizes, int n_in,
                              void* d_out, int out_size, void* d_ws, size_t ws_size,
                              hipStream_t stream)
{
    (void)in_sizes; (void)n_in; (void)out_size; (void)ws_size;
    const float* x = (const float*)d_in[0];
    const float* w_ckv = (const float*)d_in[1];
    const float* w_kv = (const float*)d_in[2];
    const float* w_cq = (const float*)d_in[3];
    const float* w_q = (const float*)d_in[4];
    const float* w_qr = (const float*)d_in[5];
    const float* w_kr = (const float*)d_in[6];
    const float* w_out = (const float*)d_in[7];
    float* out = (float*)d_out;

    char* ws = (char*)d_ws;
    size_t off = 0;
    auto take = [&](size_t elems) -> bf16* {
        bf16* p = (bf16*)(ws + off);
        off += (elems * sizeof(bf16) + 255) & ~(size_t)255;
        return p;
    };
    bf16* WCKV = take(2048ull * 512);
    bf16* WKV  = take(512ull * 4096);
    bf16* WCQ  = take(2048ull * 512);
    bf16* WQ   = take(512ull * 2048);
    bf16* WQR  = take(512ull * 1024);
    bf16* WKR  = take(512ull * 64);
    bf16* CKV  = take(4096ull * 512);   // c_kv (bf16)
    bf16* CQ   = take(4096ull * 512);   // c_q  (bf16) -- contiguous after CKV
    bf16* KV   = take(4096ull * 4096);
    bf16* QC   = take(4096ull * 2048);
    bf16* QR   = take(4096ull * 1024);
    bf16* KR   = take(4096ull * 64);
    bf16* ATT  = take(4096ull * 2048);
    // W_out (2048*2048 bf16 = 8 MB) aliases CKV+CQ (4+4 MB, dead after gemm5/6);
    // its conversion is launched after their last use.
    bf16* WOUT = CKV;

    auto cvt = [&](const float* in, bf16* o, size_t n) {
        int n4 = (int)(n >> 2);
        int blocks = (n4 + 255) / 256;
        if (blocks > 4096) blocks = 4096;
        k_cvt_f32_bf16<<<blocks, 256, 0, stream>>>(in, o, n4);
    };
    cvt(w_ckv, WCKV, 2048ull * 512);
    cvt(w_kv, WKV, 512ull * 4096);
    cvt(w_cq, WCQ, 2048ull * 512);
    cvt(w_q, WQ, 512ull * 2048);
    cvt(w_qr, WQR, 512ull * 1024);
    cvt(w_kr, WKR, 512ull * 64);

    auto gemm_a32 = [&](const float* Afp, const bf16* B, bf16* C, int M, int N, int K) {
        dim3 g((N + 127) / 128, (M + 127) / 128);
        k_gemm<true, false><<<g, 256, 0, stream>>>(nullptr, Afp, B, C, nullptr, M, N, K);
    };
    auto gemm_bf = [&](const bf16* A, const bf16* B, bf16* C, int M, int N, int K) {
        dim3 g((N + 127) / 128, (M + 127) / 128);
        k_gemm<false, false><<<g, 256, 0, stream>>>(A, nullptr, B, C, nullptr, M, N, K);
    };

    gemm_a32(x, WCKV, CKV, 4096, 512, 2048);   // c_kv = x @ W_ckv
    gemm_a32(x, WCQ, CQ, 4096, 512, 2048);     // c_q  = x @ W_cq
    gemm_bf(CKV, WKV, KV, 4096, 4096, 512);    // kv   = c_kv @ W_kv
    gemm_bf(CQ, WQ, QC, 4096, 2048, 512);      // q_c  = c_q @ W_q
    gemm_bf(CQ, WQR, QR, 4096, 1024, 512);     // q_r  = c_q @ W_qr
    gemm_bf(CKV, WKR, KR, 4096, 64, 512);      // k_r  = c_kv @ W_kr

    cvt(w_out, WOUT, 2048ull * 2048);          // safe now: CKV/CQ dead

    k_rope_q<<<8192, 256, 0, stream>>>(QR);
    k_rope_k<<<512, 256, 0, stream>>>(KR);

    k_attn<<<dim3(32, 16, 2), 256, 0, stream>>>(QC, QR, KV, KR, ATT);

    dim3 g7(16, 32);
    k_gemm<false, true><<<g7, 256, 0, stream>>>(ATT, nullptr, WOUT, nullptr, out,
                                                4096, 2048, 2048);
}

// Round 3
// 372.709 us; speedup vs baseline: 2.8742x; 2.8742x over previous
//
#include <hip/hip_runtime.h>
#include <hip/hip_bf16.h>
#include <cstdint>
#include <cstddef>

typedef __bf16 bf16;
typedef __attribute__((ext_vector_type(2))) __bf16 bf16x2;
typedef __attribute__((ext_vector_type(4))) __bf16 bf16x4;
typedef __attribute__((ext_vector_type(8))) __bf16 bf16x8;
typedef __attribute__((ext_vector_type(4))) float f32x4;

#define MFMA16(a, b, c) __builtin_amdgcn_mfma_f32_16x16x32_bf16((a), (b), (c), 0, 0, 0)
#define SCALE_F 0.08838834764831845f   // 1/sqrt(128)

__device__ __forceinline__ void gload16(const void* g, void* l) {
    __builtin_amdgcn_global_load_lds(
        (const __attribute__((address_space(1))) void*)g,
        (__attribute__((address_space(3))) void*)l, 16, 0, 0);
}

// ---------------- f32 -> bf16 transpose-convert (weights) ----------------
// in: W[Kd][Nd] f32  ->  out: WT[Nd][Kd] bf16.  32x32 tiles via LDS.
__global__ __launch_bounds__(256) void k_cvtT(const float* __restrict__ in,
                                              bf16* __restrict__ out, int Kd, int Nd)
{
    __shared__ float tile[32][33];
    const int k0 = blockIdx.y * 32, n0 = blockIdx.x * 32;
    const int t = threadIdx.x;
    const int r = t >> 3, c4 = (t & 7) * 4;
    float4 v = *(const float4*)(in + (size_t)(k0 + r) * Nd + n0 + c4);
    tile[r][c4 + 0] = v.x; tile[r][c4 + 1] = v.y;
    tile[r][c4 + 2] = v.z; tile[r][c4 + 3] = v.w;
    __syncthreads();
    bf16x4 o;
    o[0] = (bf16)tile[c4 + 0][r]; o[1] = (bf16)tile[c4 + 1][r];
    o[2] = (bf16)tile[c4 + 2][r]; o[3] = (bf16)tile[c4 + 3][r];
    *(bf16x4*)(out + (size_t)(n0 + r) * Kd + k0 + c4) = o;
}

// ---------------- bf16 MFMA GEMM, B pre-transposed ----------------
// C[M,N] = A[M,K] @ B[K,N], given BT[N][K] row-major.
// Tile: (MF*32) x 128, 4 waves (2x2), BK=32, global_load_lds width-16 staging.
template<int MF, bool AF32, bool F32OUT>
__global__ __launch_bounds__(256) void k_gemm_bt(
    const bf16* __restrict__ A, const float* __restrict__ Af,
    const bf16* __restrict__ BT,
    bf16* __restrict__ Cb, float* __restrict__ Cf,
    int M, int N, int K)
{
    __shared__ bf16 As[MF * 1024];   // [MF*32 rows][32 k] linear
    __shared__ bf16 Bs[128 * 32];    // [128 n-rows][32 k] linear

    const int t = threadIdx.x;
    const int m0 = blockIdx.y * (MF * 32);
    const int n0 = blockIdx.x * 128;
    const int wid = t >> 6, lane = t & 63;
    const int wm = (wid >> 1) * (MF * 16), wn = (wid & 1) * 64;
    const int lr = lane & 15, lk = (lane >> 4) * 8;

    const int srow = t >> 2, skc = (t & 3) << 3;       // staging row / k-chunk
    const int bn0 = min(n0 + srow, N - 1);
    const int bn1 = min(n0 + srow + 64, N - 1);

    f32x4 acc[MF][4];
    const f32x4 z = {0.f, 0.f, 0.f, 0.f};
#pragma unroll
    for (int m = 0; m < MF; ++m)
#pragma unroll
        for (int n = 0; n < 4; ++n) acc[m][n] = z;

    for (int k0 = 0; k0 < K; k0 += 32) {
        __syncthreads();
        // B tile 128x32 via async global->LDS (linear dest, lane-ordered)
        gload16(BT + (size_t)bn0 * K + k0 + skc, Bs + t * 8);
        gload16(BT + (size_t)bn1 * K + k0 + skc, Bs + (t + 256) * 8);
        // A tile (MF*32)x32
        if constexpr (AF32) {
            const float* s0 = Af + (size_t)(m0 + srow) * K + k0 + skc;
            float4 u0 = *(const float4*)s0;
            float4 u1 = *(const float4*)(s0 + 4);
            bf16x8 v;
            v[0] = (bf16)u0.x; v[1] = (bf16)u0.y; v[2] = (bf16)u0.z; v[3] = (bf16)u0.w;
            v[4] = (bf16)u1.x; v[5] = (bf16)u1.y; v[6] = (bf16)u1.z; v[7] = (bf16)u1.w;
            *(bf16x8*)(As + t * 8) = v;
            if constexpr (MF == 4) {
                const float* s1 = Af + (size_t)(m0 + srow + 64) * K + k0 + skc;
                float4 w0 = *(const float4*)s1;
                float4 w1 = *(const float4*)(s1 + 4);
                bf16x8 v2;
                v2[0] = (bf16)w0.x; v2[1] = (bf16)w0.y; v2[2] = (bf16)w0.z; v2[3] = (bf16)w0.w;
                v2[4] = (bf16)w1.x; v2[5] = (bf16)w1.y; v2[6] = (bf16)w1.z; v2[7] = (bf16)w1.w;
                *(bf16x8*)(As + (t + 256) * 8) = v2;
            }
        } else {
            gload16(A + (size_t)(m0 + srow) * K + k0 + skc, As + t * 8);
            if constexpr (MF == 4)
                gload16(A + (size_t)(m0 + srow + 64) * K + k0 + skc, As + (t + 256) * 8);
        }
        __syncthreads();

        bf16x8 af[MF], bfr[4];
#pragma unroll
        for (int m = 0; m < MF; ++m) af[m] = *(const bf16x8*)(As + (wm + m * 16 + lr) * 32 + lk);
#pragma unroll
        for (int n = 0; n < 4; ++n) bfr[n] = *(const bf16x8*)(Bs + (wn + n * 16 + lr) * 32 + lk);
#pragma unroll
        for (int m = 0; m < MF; ++m)
#pragma unroll
            for (int n = 0; n < 4; ++n)
                acc[m][n] = MFMA16(af[m], bfr[n], acc[m][n]);
    }

    const int lrow4 = (lane >> 4) * 4;
#pragma unroll
    for (int m = 0; m < MF; ++m)
#pragma unroll
        for (int n = 0; n < 4; ++n)
#pragma unroll
            for (int i = 0; i < 4; ++i) {
                int r = m0 + wm + m * 16 + lrow4 + i;
                int c = n0 + wn + n * 16 + lr;
                if (r < M && c < N) {
                    if constexpr (F32OUT) Cf[(size_t)r * N + c] = acc[m][n][i];
                    else Cb[(size_t)r * N + c] = (bf16)acc[m][n][i];
                }
            }
}

// ---------------- RoPE (in-place, bf16) ----------------
__global__ void k_rope_q(bf16* __restrict__ qr)
{
    int idx = blockIdx.x * blockDim.x + threadIdx.x;  // 4096*512 threads
    int row = idx >> 9;
    int rem = idx & 511;
    int h = rem >> 5;
    int i = rem & 31;
    int s = row & 2047;
    float ang = (float)s * __expf(-(float)i * 0.28782313662f);  // ln(10000)/32
    float c = cosf(ang), sn = sinf(ang);
    int base = (row << 10) + (h << 6) + (i << 1);
    float xe = (float)qr[base], xo = (float)qr[base + 1];
    qr[base] = (bf16)(xe * c - xo * sn);
    qr[base + 1] = (bf16)(xe * sn + xo * c);
}

__global__ void k_rope_k(bf16* __restrict__ kr)
{
    int idx = blockIdx.x * blockDim.x + threadIdx.x;  // 4096*32 threads
    int row = idx >> 5;
    int i = idx & 31;
    int s = row & 2047;
    float ang = (float)s * __expf(-(float)i * 0.28782313662f);
    float c = cosf(ang), sn = sinf(ang);
    int base = (row << 6) + (i << 1);
    float xe = (float)kr[base], xo = (float)kr[base + 1];
    kr[base] = (bf16)(xe * c - xo * sn);
    kr[base + 1] = (bf16)(xe * sn + xo * c);
}

// ---------------- causal MLA attention (flash-style, balanced pairs) ----------------
// Flat grid of 512 blocks. Block L -> (p, h, b) with XCD-grouped mapping so all
// 16 q-tile-pair blocks of one (b,h) share an XCD's L2 for KV.
// Each block: passes qt=p and qt=31-p  (p+1 + 32-p = 33 KV tiles, balanced).
__global__ __launch_bounds__(256) void k_attn(
    const bf16* __restrict__ qc, const bf16* __restrict__ qr,
    const bf16* __restrict__ kv, const bf16* __restrict__ kr,
    bf16* __restrict__ att)
{
    __shared__ bf16 Ks[64 * 200];   // [key][feat 0..191], stride 200
    __shared__ bf16 Vt[128 * 72];   // [feat][key], stride 72
    __shared__ bf16 Pw[4][16 * 72]; // per-wave P tile

    const int L = blockIdx.x;
    const int p = (L >> 3) & 15;
    const int bh = (L & 7) * 4 + (L >> 7);
    const int h = bh & 15, b = bh >> 4;

    const int t = threadIdx.x;
    const int wid = t >> 6, lane = t & 63;
    const int lr = lane & 15, lk = (lane >> 4) * 8, lrow4 = (lane >> 4) * 4;
    const size_t rowbase = (size_t)b * 2048;

    const int vkp = lane & 31;              // key-pair 0..31 (spreads write banks)
    const int vf0 = (lane >> 5) + 2 * wid;  // feat-chunk base 0..7

    const f32x4 z = {0.f, 0.f, 0.f, 0.f};

#pragma unroll 1
    for (int pass = 0; pass < 2; ++pass) {
        const int qt = pass ? 31 - p : p;
        const int qrow = qt * 64 + wid * 16;

        bf16x8 qf[6];
        {
            const bf16* qp = qc + (rowbase + qrow + lr) * 2048 + h * 128;
#pragma unroll
            for (int ks = 0; ks < 4; ++ks) qf[ks] = *(const bf16x8*)(qp + ks * 32 + lk);
            const bf16* qp2 = qr + (rowbase + qrow + lr) * 1024 + h * 64;
#pragma unroll
            for (int ks = 0; ks < 2; ++ks) qf[4 + ks] = *(const bf16x8*)(qp2 + ks * 32 + lk);
        }

        float mrow[4], lsum[4];
        f32x4 o[8];
#pragma unroll
        for (int i = 0; i < 4; ++i) { mrow[i] = -3e38f; lsum[i] = 0.f; }
#pragma unroll
        for (int n = 0; n < 8; ++n) o[n] = z;

#pragma unroll 1
        for (int kt = 0; kt <= qt; ++kt) {
            const int kb = kt * 64;
            __syncthreads();
            // K_c 64x128
#pragma unroll
            for (int i = 0; i < 4; ++i) {
                int idx = t + i * 256;
                int row = idx >> 4, fc = (idx & 15) << 3;
                bf16x8 v = *(const bf16x8*)(kv + (rowbase + kb + row) * 4096 + h * 128 + fc);
                *(bf16x8*)(Ks + row * 200 + fc) = v;
            }
            // K_r 64x64
#pragma unroll
            for (int i = 0; i < 2; ++i) {
                int idx = t + i * 256;
                int row = idx >> 3, fc = (idx & 7) << 3;
                bf16x8 v = *(const bf16x8*)(kr + (rowbase + kb + row) * 64 + fc);
                *(bf16x8*)(Ks + row * 200 + 128 + fc) = v;
            }
            // V 64x128 -> Vt[feat][key]: dword-pair writes, 32 distinct key-pairs
            // per instruction -> 2-way banks (was 32-way scalar scatter).
#pragma unroll
            for (int it = 0; it < 2; ++it) {
                const int fci = vf0 + 8 * it;
                const bf16* vs = kv + (rowbase + kb + 2 * vkp) * 4096 + 2048 + h * 128 + fci * 8;
                bf16x8 v0 = *(const bf16x8*)vs;
                bf16x8 v1 = *(const bf16x8*)(vs + 4096);
#pragma unroll
                for (int j = 0; j < 8; ++j) {
                    bf16x2 pr; pr[0] = v0[j]; pr[1] = v1[j];
                    *(bf16x2*)(Vt + (fci * 8 + j) * 72 + 2 * vkp) = pr;
                }
            }
            __syncthreads();

            // S = Q K^T
            f32x4 sacc[4];
#pragma unroll
            for (int kg = 0; kg < 4; ++kg) {
                f32x4 s = z;
#pragma unroll
                for (int ks = 0; ks < 6; ++ks) {
                    bf16x8 kf = *(const bf16x8*)(Ks + (kg * 16 + lr) * 200 + ks * 32 + lk);
                    s = MFMA16(qf[ks], kf, s);
                }
                sacc[kg] = s;
            }

            // Mask needed iff tile's max key (kb+63) can exceed the wave's FIRST
            // row (qrow).  (Round-1 bug: compared against qrow+15, which skipped
            // masking for wave 3 on the diagonal tile -> acausal leakage.)
            const bool domask = (kb + 63) > qrow;
            float rmax[4];
#pragma unroll
            for (int i = 0; i < 4; ++i) {
                int qi = qrow + lrow4 + i;
                float mx = -3e38f;
#pragma unroll
                for (int kg = 0; kg < 4; ++kg) {
                    float v = sacc[kg][i] * SCALE_F;
                    if (domask && (kb + kg * 16 + lr) > qi) v = -3e38f;
                    sacc[kg][i] = v;
                    mx = fmaxf(mx, v);
                }
                rmax[i] = mx;
            }
#pragma unroll
            for (int d = 1; d < 16; d <<= 1)
#pragma unroll
                for (int i = 0; i < 4; ++i)
                    rmax[i] = fmaxf(rmax[i], __shfl_xor(rmax[i], d, 64));

            float scl[4];
#pragma unroll
            for (int i = 0; i < 4; ++i) {
                float mnew = fmaxf(mrow[i], rmax[i]);
                scl[i] = __expf(mrow[i] - mnew);
                mrow[i] = mnew;
            }
            float rsum[4] = {0.f, 0.f, 0.f, 0.f};
#pragma unroll
            for (int kg = 0; kg < 4; ++kg)
#pragma unroll
                for (int i = 0; i < 4; ++i) {
                    float pv = __expf(sacc[kg][i] - mrow[i]);
                    sacc[kg][i] = pv;
                    rsum[i] += pv;
                }
#pragma unroll
            for (int d = 1; d < 16; d <<= 1)
#pragma unroll
                for (int i = 0; i < 4; ++i) rsum[i] += __shfl_xor(rsum[i], d, 64);
#pragma unroll
            for (int i = 0; i < 4; ++i) lsum[i] = lsum[i] * scl[i] + rsum[i];
#pragma unroll
            for (int n = 0; n < 8; ++n)
#pragma unroll
                for (int i = 0; i < 4; ++i) o[n][i] *= scl[i];

            // P -> per-wave LDS (re-fragment); same-wave DS ordering
#pragma unroll
            for (int kg = 0; kg < 4; ++kg)
#pragma unroll
                for (int i = 0; i < 4; ++i)
                    Pw[wid][(lrow4 + i) * 72 + kg * 16 + lr] = (bf16)sacc[kg][i];

            // O += P V
#pragma unroll
            for (int ks = 0; ks < 2; ++ks) {
                bf16x8 pa = *(const bf16x8*)(&Pw[wid][lr * 72 + ks * 32 + lk]);
#pragma unroll
                for (int n = 0; n < 8; ++n) {
                    bf16x8 vf = *(const bf16x8*)(Vt + (n * 16 + lr) * 72 + ks * 32 + lk);
                    o[n] = MFMA16(pa, vf, o[n]);
                }
            }
        }

#pragma unroll
        for (int i = 0; i < 4; ++i) {
            float inv = 1.f / lsum[i];
            size_t orow = (rowbase + qrow + lrow4 + i) * 2048 + h * 128;
#pragma unroll
            for (int n = 0; n < 8; ++n)
                att[orow + n * 16 + lr] = (bf16)(o[n][i] * inv);
        }
    }
}

// ---------------- host launch ----------------
extern "C" void kernel_launch(void* const* d_in, const int* in_sizes, int n_in,
                              void* d_out, int out_size, void* d_ws, size_t ws_size,
                              hipStream_t stream)
{
    (void)in_sizes; (void)n_in; (void)out_size; (void)ws_size;
    const float* x = (const float*)d_in[0];
    const float* w_ckv = (const float*)d_in[1];
    const float* w_kv = (const float*)d_in[2];
    const float* w_cq = (const float*)d_in[3];
    const float* w_q = (const float*)d_in[4];
    const float* w_qr = (const float*)d_in[5];
    const float* w_kr = (const float*)d_in[6];
    const float* w_out = (const float*)d_in[7];
    float* out = (float*)d_out;

    char* ws = (char*)d_ws;
    size_t off = 0;
    auto take = [&](size_t elems) -> bf16* {
        bf16* p = (bf16*)(ws + off);
        off += (elems * sizeof(bf16) + 255) & ~(size_t)255;
        return p;
    };
    // transposed weights: WT[N][K]
    bf16* WCKVT = take(512ull * 2048);
    bf16* WKVT  = take(4096ull * 512);
    bf16* WCQT  = take(512ull * 2048);
    bf16* WQT   = take(2048ull * 512);
    bf16* WQRT  = take(1024ull * 512);
    bf16* WKRT  = take(64ull * 512);
    bf16* CKV   = take(4096ull * 512);
    bf16* CQ    = take(4096ull * 512);
    bf16* KV    = take(4096ull * 4096);
    bf16* QC    = take(4096ull * 2048);
    bf16* QR    = take(4096ull * 1024);
    bf16* KR    = take(4096ull * 64);
    bf16* ATT   = take(4096ull * 2048);
    bf16* WOUTT = CKV;  // 8 MB alias over CKV+CQ (dead after last projection GEMMs)

    auto cvtT = [&](const float* in, bf16* o, int K, int N) {
        k_cvtT<<<dim3(N / 32, K / 32), 256, 0, stream>>>(in, o, K, N);
    };
    cvtT(w_ckv, WCKVT, 2048, 512);
    cvtT(w_kv, WKVT, 512, 4096);
    cvtT(w_cq, WCQT, 2048, 512);
    cvtT(w_q, WQT, 512, 2048);
    cvtT(w_qr, WQRT, 512, 1024);
    cvtT(w_kr, WKRT, 512, 64);

    // c_kv = x @ W_ckv ; c_q = x @ W_cq  (A=f32, 64-row tiles -> 256 blocks)
    k_gemm_bt<2, true, false><<<dim3(4, 64), 256, 0, stream>>>(
        nullptr, x, WCKVT, CKV, nullptr, 4096, 512, 2048);
    k_gemm_bt<2, true, false><<<dim3(4, 64), 256, 0, stream>>>(
        nullptr, x, WCQT, CQ, nullptr, 4096, 512, 2048);
    // kv = c_kv @ W_kv
    k_gemm_bt<4, false, false><<<dim3(32, 32), 256, 0, stream>>>(
        CKV, nullptr, WKVT, KV, nullptr, 4096, 4096, 512);
    // q_c = c_q @ W_q
    k_gemm_bt<4, false, false><<<dim3(16, 32), 256, 0, stream>>>(
        CQ, nullptr, WQT, QC, nullptr, 4096, 2048, 512);
    // q_r = c_q @ W_qr
    k_gemm_bt<4, false, false><<<dim3(8, 32), 256, 0, stream>>>(
        CQ, nullptr, WQRT, QR, nullptr, 4096, 1024, 512);
    // k_r = c_kv @ W_kr
    k_gemm_bt<2, false, false><<<dim3(1, 64), 256, 0, stream>>>(
        CKV, nullptr, WKRT, KR, nullptr, 4096, 64, 512);

    cvtT(w_out, WOUTT, 2048, 2048);  // safe: CKV/CQ dead now

    k_rope_q<<<8192, 256, 0, stream>>>(QR);
    k_rope_k<<<512, 256, 0, stream>>>(KR);

    k_attn<<<512, 256, 0, stream>>>(QC, QR, KV, KR, ATT);

    // out = att @ W_out
    k_gemm_bt<4, false, true><<<dim3(16, 32), 256, 0, stream>>>(
        ATT, nullptr, WOUTT, nullptr, out, 4096, 2048, 2048);
}

// Round 4
// 332.865 us; speedup vs baseline: 3.2183x; 1.1197x over previous
//
#include <hip/hip_runtime.h>
#include <hip/hip_bf16.h>
#include <cstdint>
#include <cstddef>

typedef __bf16 bf16;
typedef __attribute__((ext_vector_type(2))) __bf16 bf16x2;
typedef __attribute__((ext_vector_type(4))) __bf16 bf16x4;
typedef __attribute__((ext_vector_type(8))) __bf16 bf16x8;
typedef __attribute__((ext_vector_type(4))) float f32x4;

#define MFMA16(a, b, c) __builtin_amdgcn_mfma_f32_16x16x32_bf16((a), (b), (c), 0, 0, 0)
#define SCALE_F 0.08838834764831845f   // 1/sqrt(128)

// Packed-layout constants:
//  QCR row: [0..2047]=q_c (h*128+d), [2048..3071]=q_r (h*64+r)    stride 3072
//  KVKR row: [0..2047]=k_c, [2048..4095]=v, [4096..4159]=k_r      stride 4160
#define QCR_STRIDE 3072
#define KV_STRIDE  4160

__device__ __forceinline__ void gload16(const void* g, void* l) {
    __builtin_amdgcn_global_load_lds(
        (const __attribute__((address_space(1))) void*)g,
        (__attribute__((address_space(3))) void*)l, 16, 0, 0);
}

// ---------------- f32 -> bf16 transpose-convert (weights) ----------------
// in: W[Kd][Nd] f32  ->  out: WT[Nd][Kd] bf16.  32x32 tiles via LDS.
__global__ __launch_bounds__(256) void k_cvtT(const float* __restrict__ in,
                                              bf16* __restrict__ out, int Kd, int Nd)
{
    __shared__ float tile[32][33];
    const int k0 = blockIdx.y * 32, n0 = blockIdx.x * 32;
    const int t = threadIdx.x;
    const int r = t >> 3, c4 = (t & 7) * 4;
    float4 v = *(const float4*)(in + (size_t)(k0 + r) * Nd + n0 + c4);
    tile[r][c4 + 0] = v.x; tile[r][c4 + 1] = v.y;
    tile[r][c4 + 2] = v.z; tile[r][c4 + 3] = v.w;
    __syncthreads();
    bf16x4 o;
    o[0] = (bf16)tile[c4 + 0][r]; o[1] = (bf16)tile[c4 + 1][r];
    o[2] = (bf16)tile[c4 + 2][r]; o[3] = (bf16)tile[c4 + 3][r];
    *(bf16x4*)(out + (size_t)(n0 + r) * Kd + k0 + c4) = o;
}

// ---------------- bf16 MFMA GEMM, B pre-transposed, 2-phase dbuf ----------------
// C[M,N] = A[M,K] @ B[K,N], given BT[N][K] row-major.  A row stride = lda.
// Tile: 128 x 128, 4 waves (2x2), BK=32, global_load_lds width-16 staging,
// double-buffered LDS: stage(t+1) issued BEFORE compute(t); one barrier/iter
// (its vmcnt(0)+lgkmcnt(0) drain completes the prefetch and orders reuse).
template<bool AF32, bool F32OUT>
__global__ __launch_bounds__(256) void k_gemm_bt(
    const bf16* __restrict__ A, const float* __restrict__ Af,
    const bf16* __restrict__ BT,
    bf16* __restrict__ Cb, float* __restrict__ Cf,
    int M, int N, int K, int lda)
{
    __shared__ bf16 As[2][4096];   // [128 rows][32 k] linear
    __shared__ bf16 Bs[2][4096];   // [128 n-rows][32 k] linear

    const int t = threadIdx.x;
    const int m0 = blockIdx.y * 128;
    const int n0 = blockIdx.x * 128;
    const int wid = t >> 6, lane = t & 63;
    const int wm = (wid >> 1) * 64, wn = (wid & 1) * 64;
    const int lr = lane & 15, lk = (lane >> 4) * 8;

    const int srow = t >> 2, skc = (t & 3) << 3;       // staging row / k-chunk
    const int bn0 = min(n0 + srow, N - 1);
    const int bn1 = min(n0 + srow + 64, N - 1);

    f32x4 acc[4][4];
    const f32x4 z = {0.f, 0.f, 0.f, 0.f};
#pragma unroll
    for (int m = 0; m < 4; ++m)
#pragma unroll
        for (int n = 0; n < 4; ++n) acc[m][n] = z;

    auto stage = [&](int buf, int k0) {
        gload16(BT + (size_t)bn0 * K + k0 + skc, &Bs[buf][t * 8]);
        gload16(BT + (size_t)bn1 * K + k0 + skc, &Bs[buf][(t + 256) * 8]);
        if constexpr (AF32) {
            const float* s0 = Af + (size_t)(m0 + srow) * lda + k0 + skc;
            float4 u0 = *(const float4*)s0;
            float4 u1 = *(const float4*)(s0 + 4);
            bf16x8 v;
            v[0] = (bf16)u0.x; v[1] = (bf16)u0.y; v[2] = (bf16)u0.z; v[3] = (bf16)u0.w;
            v[4] = (bf16)u1.x; v[5] = (bf16)u1.y; v[6] = (bf16)u1.z; v[7] = (bf16)u1.w;
            *(bf16x8*)(&As[buf][t * 8]) = v;
            const float* s1 = Af + (size_t)(m0 + srow + 64) * lda + k0 + skc;
            float4 w0 = *(const float4*)s1;
            float4 w1 = *(const float4*)(s1 + 4);
            bf16x8 v2;
            v2[0] = (bf16)w0.x; v2[1] = (bf16)w0.y; v2[2] = (bf16)w0.z; v2[3] = (bf16)w0.w;
            v2[4] = (bf16)w1.x; v2[5] = (bf16)w1.y; v2[6] = (bf16)w1.z; v2[7] = (bf16)w1.w;
            *(bf16x8*)(&As[buf][(t + 256) * 8]) = v2;
        } else {
            gload16(A + (size_t)(m0 + srow) * lda + k0 + skc, &As[buf][t * 8]);
            gload16(A + (size_t)(m0 + srow + 64) * lda + k0 + skc, &As[buf][(t + 256) * 8]);
        }
    };

    stage(0, 0);
    __syncthreads();

    for (int k0 = 0; k0 < K; k0 += 32) {
        const int cur = (k0 >> 5) & 1;
        if (k0 + 32 < K) stage(cur ^ 1, k0 + 32);   // prefetch next tile (async)

        bf16x8 af[4], bfr[4];
#pragma unroll
        for (int m = 0; m < 4; ++m) af[m] = *(const bf16x8*)(&As[cur][(wm + m * 16 + lr) * 32 + lk]);
#pragma unroll
        for (int n = 0; n < 4; ++n) bfr[n] = *(const bf16x8*)(&Bs[cur][(wn + n * 16 + lr) * 32 + lk]);
#pragma unroll
        for (int m = 0; m < 4; ++m)
#pragma unroll
            for (int n = 0; n < 4; ++n)
                acc[m][n] = MFMA16(af[m], bfr[n], acc[m][n]);

        __syncthreads();   // drains vmcnt (prefetch landed) + orders LDS reuse
    }

    const int lrow4 = (lane >> 4) * 4;
#pragma unroll
    for (int m = 0; m < 4; ++m)
#pragma unroll
        for (int n = 0; n < 4; ++n)
#pragma unroll
            for (int i = 0; i < 4; ++i) {
                int r = m0 + wm + m * 16 + lrow4 + i;
                int c = n0 + wn + n * 16 + lr;
                if (r < M && c < N) {
                    if constexpr (F32OUT) Cf[(size_t)r * N + c] = acc[m][n][i];
                    else Cb[(size_t)r * N + c] = (bf16)acc[m][n][i];
                }
            }
}

// ---------------- RoPE (in-place, bf16, packed layouts) ----------------
__global__ void k_rope_q(bf16* __restrict__ qcr)
{
    int idx = blockIdx.x * blockDim.x + threadIdx.x;  // 4096*512 threads
    int row = idx >> 9;
    int rem = idx & 511;
    int h = rem >> 5;
    int i = rem & 31;
    int s = row & 2047;
    float ang = (float)s * __expf(-(float)i * 0.28782313662f);  // ln(10000)/32
    float c = cosf(ang), sn = sinf(ang);
    size_t base = (size_t)row * QCR_STRIDE + 2048 + h * 64 + (i << 1);
    float xe = (float)qcr[base], xo = (float)qcr[base + 1];
    qcr[base] = (bf16)(xe * c - xo * sn);
    qcr[base + 1] = (bf16)(xe * sn + xo * c);
}

__global__ void k_rope_k(bf16* __restrict__ kvkr)
{
    int idx = blockIdx.x * blockDim.x + threadIdx.x;  // 4096*32 threads
    int row = idx >> 5;
    int i = idx & 31;
    int s = row & 2047;
    float ang = (float)s * __expf(-(float)i * 0.28782313662f);
    float c = cosf(ang), sn = sinf(ang);
    size_t base = (size_t)row * KV_STRIDE + 4096 + (i << 1);
    float xe = (float)kvkr[base], xo = (float)kvkr[base + 1];
    kvkr[base] = (bf16)(xe * c - xo * sn);
    kvkr[base + 1] = (bf16)(xe * sn + xo * c);
}

// ---------------- causal MLA attention (flash-style, balanced pairs) ----------------
// Flat grid of 512 blocks. Block L -> (p, h, b) with XCD-grouped mapping so all
// 16 q-tile-pair blocks of one (b,h) share an XCD's L2 for KV.
// Each block: passes qt=p and qt=31-p  (p+1 + 32-p = 33 KV tiles, balanced).
__global__ __launch_bounds__(256) void k_attn(
    const bf16* __restrict__ qcr, const bf16* __restrict__ kvkr,
    bf16* __restrict__ att)
{
    __shared__ bf16 Ks[64 * 200];   // [key][feat 0..191], stride 200
    __shared__ bf16 Vt[128 * 72];   // [feat][key], stride 72
    __shared__ bf16 Pw[4][16 * 72]; // per-wave P tile

    const int L = blockIdx.x;
    const int p = (L >> 3) & 15;
    const int bh = (L & 7) * 4 + (L >> 7);
    const int h = bh & 15, b = bh >> 4;

    const int t = threadIdx.x;
    const int wid = t >> 6, lane = t & 63;
    const int lr = lane & 15, lk = (lane >> 4) * 8, lrow4 = (lane >> 4) * 4;
    const size_t rowbase = (size_t)b * 2048;

    const int vkp = lane & 31;              // key-pair 0..31 (spreads write banks)
    const int vf0 = (lane >> 5) + 2 * wid;  // feat-chunk base 0..7

    const f32x4 z = {0.f, 0.f, 0.f, 0.f};

#pragma unroll 1
    for (int pass = 0; pass < 2; ++pass) {
        const int qt = pass ? 31 - p : p;
        const int qrow = qt * 64 + wid * 16;

        bf16x8 qf[6];
        {
            const bf16* qp = qcr + (rowbase + qrow + lr) * QCR_STRIDE + h * 128;
#pragma unroll
            for (int ks = 0; ks < 4; ++ks) qf[ks] = *(const bf16x8*)(qp + ks * 32 + lk);
            const bf16* qp2 = qcr + (rowbase + qrow + lr) * QCR_STRIDE + 2048 + h * 64;
#pragma unroll
            for (int ks = 0; ks < 2; ++ks) qf[4 + ks] = *(const bf16x8*)(qp2 + ks * 32 + lk);
        }

        float mrow[4], lsum[4];
        f32x4 o[8];
#pragma unroll
        for (int i = 0; i < 4; ++i) { mrow[i] = -3e38f; lsum[i] = 0.f; }
#pragma unroll
        for (int n = 0; n < 8; ++n) o[n] = z;

#pragma unroll 1
        for (int kt = 0; kt <= qt; ++kt) {
            const int kb = kt * 64;
            __syncthreads();
            // K_c 64x128
#pragma unroll
            for (int i = 0; i < 4; ++i) {
                int idx = t + i * 256;
                int row = idx >> 4, fc = (idx & 15) << 3;
                bf16x8 v = *(const bf16x8*)(kvkr + (rowbase + kb + row) * KV_STRIDE + h * 128 + fc);
                *(bf16x8*)(Ks + row * 200 + fc) = v;
            }
            // K_r 64x64
#pragma unroll
            for (int i = 0; i < 2; ++i) {
                int idx = t + i * 256;
                int row = idx >> 3, fc = (idx & 7) << 3;
                bf16x8 v = *(const bf16x8*)(kvkr + (rowbase + kb + row) * KV_STRIDE + 4096 + fc);
                *(bf16x8*)(Ks + row * 200 + 128 + fc) = v;
            }
            // V 64x128 -> Vt[feat][key]: dword-pair writes, 32 distinct key-pairs
            // per instruction -> 2-way banks.
#pragma unroll
            for (int it = 0; it < 2; ++it) {
                const int fci = vf0 + 8 * it;
                const bf16* vs = kvkr + (rowbase + kb + 2 * vkp) * KV_STRIDE + 2048 + h * 128 + fci * 8;
                bf16x8 v0 = *(const bf16x8*)vs;
                bf16x8 v1 = *(const bf16x8*)(vs + KV_STRIDE);
#pragma unroll
                for (int j = 0; j < 8; ++j) {
                    bf16x2 pr; pr[0] = v0[j]; pr[1] = v1[j];
                    *(bf16x2*)(Vt + (fci * 8 + j) * 72 + 2 * vkp) = pr;
                }
            }
            __syncthreads();

            // S = Q K^T
            f32x4 sacc[4];
#pragma unroll
            for (int kg = 0; kg < 4; ++kg) {
                f32x4 s = z;
#pragma unroll
                for (int ks = 0; ks < 6; ++ks) {
                    bf16x8 kf = *(const bf16x8*)(Ks + (kg * 16 + lr) * 200 + ks * 32 + lk);
                    s = MFMA16(qf[ks], kf, s);
                }
                sacc[kg] = s;
            }

            // Mask needed iff tile's max key (kb+63) can exceed the wave's FIRST row.
            const bool domask = (kb + 63) > qrow;
            float rmax[4];
#pragma unroll
            for (int i = 0; i < 4; ++i) {
                int qi = qrow + lrow4 + i;
                float mx = -3e38f;
#pragma unroll
                for (int kg = 0; kg < 4; ++kg) {
                    float v = sacc[kg][i] * SCALE_F;
                    if (domask && (kb + kg * 16 + lr) > qi) v = -3e38f;
                    sacc[kg][i] = v;
                    mx = fmaxf(mx, v);
                }
                rmax[i] = mx;
            }
#pragma unroll
            for (int d = 1; d < 16; d <<= 1)
#pragma unroll
                for (int i = 0; i < 4; ++i)
                    rmax[i] = fmaxf(rmax[i], __shfl_xor(rmax[i], d, 64));

            float scl[4];
#pragma unroll
            for (int i = 0; i < 4; ++i) {
                float mnew = fmaxf(mrow[i], rmax[i]);
                scl[i] = __expf(mrow[i] - mnew);
                mrow[i] = mnew;
            }
            float rsum[4] = {0.f, 0.f, 0.f, 0.f};
#pragma unroll
            for (int kg = 0; kg < 4; ++kg)
#pragma unroll
                for (int i = 0; i < 4; ++i) {
                    float pv = __expf(sacc[kg][i] - mrow[i]);
                    sacc[kg][i] = pv;
                    rsum[i] += pv;
                }
#pragma unroll
            for (int d = 1; d < 16; d <<= 1)
#pragma unroll
                for (int i = 0; i < 4; ++i) rsum[i] += __shfl_xor(rsum[i], d, 64);
#pragma unroll
            for (int i = 0; i < 4; ++i) lsum[i] = lsum[i] * scl[i] + rsum[i];
#pragma unroll
            for (int n = 0; n < 8; ++n)
#pragma unroll
                for (int i = 0; i < 4; ++i) o[n][i] *= scl[i];

            // P -> per-wave LDS (re-fragment); same-wave DS ordering
#pragma unroll
            for (int kg = 0; kg < 4; ++kg)
#pragma unroll
                for (int i = 0; i < 4; ++i)
                    Pw[wid][(lrow4 + i) * 72 + kg * 16 + lr] = (bf16)sacc[kg][i];

            // O += P V
#pragma unroll
            for (int ks = 0; ks < 2; ++ks) {
                bf16x8 pa = *(const bf16x8*)(&Pw[wid][lr * 72 + ks * 32 + lk]);
#pragma unroll
                for (int n = 0; n < 8; ++n) {
                    bf16x8 vf = *(const bf16x8*)(Vt + (n * 16 + lr) * 72 + ks * 32 + lk);
                    o[n] = MFMA16(pa, vf, o[n]);
                }
            }
        }

#pragma unroll
        for (int i = 0; i < 4; ++i) {
            float inv = 1.f / lsum[i];
            size_t orow = (rowbase + qrow + lrow4 + i) * 2048 + h * 128;
#pragma unroll
            for (int n = 0; n < 8; ++n)
                att[orow + n * 16 + lr] = (bf16)(o[n][i] * inv);
        }
    }
}

// ---------------- host launch ----------------
extern "C" void kernel_launch(void* const* d_in, const int* in_sizes, int n_in,
                              void* d_out, int out_size, void* d_ws, size_t ws_size,
                              hipStream_t stream)
{
    (void)in_sizes; (void)n_in; (void)out_size; (void)ws_size;
    const float* x = (const float*)d_in[0];
    const float* w_ckv = (const float*)d_in[1];
    const float* w_kv = (const float*)d_in[2];
    const float* w_cq = (const float*)d_in[3];
    const float* w_q = (const float*)d_in[4];
    const float* w_qr = (const float*)d_in[5];
    const float* w_kr = (const float*)d_in[6];
    const float* w_out = (const float*)d_in[7];
    float* out = (float*)d_out;

    char* ws = (char*)d_ws;
    size_t off = 0;
    auto take = [&](size_t elems) -> bf16* {
        bf16* p = (bf16*)(ws + off);
        off += (elems * sizeof(bf16) + 255) & ~(size_t)255;
        return p;
    };
    // merged transposed weights
    bf16* WCT    = take(1024ull * 2048);   // [ckv|cq]^T : rows 0-511 ckv, 512-1023 cq
    bf16* WKVKRT = take(4160ull * 512);    // [kv|kr]^T  : rows 0-4095 kv, 4096-4159 kr
    bf16* WQQRT  = take(3072ull * 512);    // [q|qr]^T   : rows 0-2047 q, 2048-3071 qr
    bf16* C      = take(4096ull * 1024);   // [c_kv | c_q] packed, stride 1024
    bf16* KVKR   = take(4096ull * 4160);   // [k_c | v | k_r] packed, stride 4160
    bf16* QCR    = take(4096ull * 3072);   // [q_c | q_r] packed, stride 3072
    bf16* ATT    = take(4096ull * 2048);
    bf16* WOUTT  = C;  // 8 MB alias (C dead after the two K=512 GEMMs)

    auto cvtT = [&](const float* in, bf16* o, int K, int N) {
        k_cvtT<<<dim3(N / 32, K / 32), 256, 0, stream>>>(in, o, K, N);
    };
    cvtT(w_ckv, WCT, 2048, 512);
    cvtT(w_cq, WCT + 512ull * 2048, 2048, 512);
    cvtT(w_kv, WKVKRT, 512, 4096);
    cvtT(w_kr, WKVKRT + 4096ull * 512, 512, 64);
    cvtT(w_q, WQQRT, 512, 2048);
    cvtT(w_qr, WQQRT + 2048ull * 512, 512, 1024);

    // C = x @ [W_ckv | W_cq]   (M=4096, N=1024, K=2048, A=f32)
    k_gemm_bt<true, false><<<dim3(8, 32), 256, 0, stream>>>(
        nullptr, x, WCT, C, nullptr, 4096, 1024, 2048, 2048);
    // KVKR = c_kv @ [W_kv | W_kr]   (N=4160, K=512)
    k_gemm_bt<false, false><<<dim3(33, 32), 256, 0, stream>>>(
        C, nullptr, WKVKRT, KVKR, nullptr, 4096, 4160, 512, 1024);
    // QCR = c_q @ [W_q | W_qr]   (N=3072, K=512)
    k_gemm_bt<false, false><<<dim3(24, 32), 256, 0, stream>>>(
        C + 512, nullptr, WQQRT, QCR, nullptr, 4096, 3072, 512, 1024);

    cvtT(w_out, WOUTT, 2048, 2048);  // safe: C dead now

    k_rope_q<<<8192, 256, 0, stream>>>(QCR);
    k_rope_k<<<512, 256, 0, stream>>>(KVKR);

    k_attn<<<512, 256, 0, stream>>>(QCR, KVKR, ATT);

    // out = att @ W_out   (N=2048, K=2048, f32 out)
    k_gemm_bt<false, true><<<dim3(16, 32), 256, 0, stream>>>(
        ATT, nullptr, WOUTT, nullptr, out, 4096, 2048, 2048, 2048);
}